// Round 6
// baseline (22.549 us; speedup 1.0000x reference)
//
#include <hip/hip_runtime.h>

#define C_DIM 32
#define M_DIM 64
#define NG    8            // NGEN
#define TAB   (M_DIM * NG) // 512
#define ST    9            // padded stride for m-indexed LDS tables
#define BST   520          // padded c-stride (floats) for staged B
#define NPB   256          // nodes per D2 block (== threads)
#define KCH   8            // consecutive nodes per thread in like phase

// ---------------------------------------------------------------------------
// D1: blocks [0,nzb): zero out_like (required every replay: D2 accumulates
// atomically). Block nzb: compute the 3x512 (m,g) tables from LDS-staged B.
// ---------------------------------------------------------------------------
__global__ void __launch_bounds__(512)
cgmm_prep(const float* __restrict__ B, const float* __restrict__ Pi,
          float* __restrict__ tab, float* __restrict__ out_like,
          int G, int nzb) {
    const int tid = threadIdx.x;

    if ((int)blockIdx.x < nzb) {
        float4* z4 = (float4*)out_like;
        const int nz4 = G * NG / 4;
        for (int i = blockIdx.x * 512 + tid; i < nz4; i += nzb * 512)
            z4[i] = make_float4(0.f, 0.f, 0.f, 0.f);
        return;
    }

    // ---- tables block ----
    __shared__ float Bs[C_DIM * BST];     // padded c-stride
    __shared__ float Pis[C_DIM * NG];
    __shared__ float lsePi_s[NG];
    __shared__ float K_s[C_DIM * NG];     // Pi - lseB - lsePi

    {
        const float4* B4 = (const float4*)B;
        float4* Bs4 = (float4*)Bs;
        #pragma unroll
        for (int i = tid; i < (C_DIM * M_DIM * NG) / 4; i += 512)
            Bs4[(i >> 7) * (BST / 4) + (i & 127)] = B4[i];
        if (tid < C_DIM * NG / 4) ((float4*)Pis)[tid] = ((const float4*)Pi)[tid];
    }
    __syncthreads();

    if (tid < NG) {
        float mx = -1e30f;
        #pragma unroll
        for (int c = 0; c < C_DIM; ++c) mx = fmaxf(mx, Pis[c * NG + tid]);
        float s = 0.f;
        #pragma unroll
        for (int c = 0; c < C_DIM; ++c) s += expf(Pis[c * NG + tid] - mx);
        lsePi_s[tid] = logf(s) + mx;
    }
    __syncthreads();

    if (tid < C_DIM * NG) {   // lanes=(c,g): conflict-free (bank = lane%32)
        const int c = tid >> 3, g = tid & 7;
        const float* bp = Bs + c * BST + g;
        float mx = -1e30f;
        #pragma unroll
        for (int m = 0; m < M_DIM; ++m) mx = fmaxf(mx, bp[m * NG]);
        float s = 0.f;
        #pragma unroll
        for (int m = 0; m < M_DIM; ++m) s += expf(bp[m * NG] - mx);
        K_s[tid] = Pis[tid] - (logf(s) + mx) - lsePi_s[g];
    }
    __syncthreads();

    {   // 512 threads = (m,g) pairs
        const int m = tid >> 3, g = tid & 7;
        float L[C_DIM];
        float best = -1e30f; int bidx = 0;
        #pragma unroll
        for (int c = 0; c < C_DIM; ++c) {
            float v = Bs[c * BST + m * NG + g] + K_s[c * NG + g];
            L[c] = v;
            if (v > best) { best = v; bidx = c; }   // strict >, first max
        }
        float se = 0.f, la = 0.f;
        #pragma unroll
        for (int c = 0; c < C_DIM; ++c) {
            float e = expf(L[c] - best);
            se += e; la += e * L[c];
        }
        tab[tid]           = la / se;     // like
        tab[TAB + tid]     = 1.f / se;    // hval = max posterior
        tab[2 * TAB + tid] = (float)bidx; // hidx
    }
}

// ---------------------------------------------------------------------------
// D2: node-parallel, 256 nodes per 256-thread block.
//  phase A: (s,g) striped -> hv/hi stores, lane addr = base*8 + tid (256B/wave)
//  phase B: thread owns 8 CONSECUTIVE nodes (fixed g): register run-accumulate
//           of like over sorted graph ids, LDS atomic flush per boundary
//  phase C: one global float atomicAdd per local (graph,g) partial
// ---------------------------------------------------------------------------
__global__ void __launch_bounds__(256)
cgmm_nodes(const int* __restrict__ x, const int* __restrict__ batch,
           const float* __restrict__ tab,
           float* __restrict__ out_like, float* __restrict__ out_hv,
           float* __restrict__ out_hi, int N) {
    __shared__ float like_s[M_DIM * ST];
    __shared__ float hval_s[M_DIM * ST];
    __shared__ float hidx_s[M_DIM * ST];
    __shared__ int   xs_s[NPB];
    __shared__ int   bs_s[NPB];
    __shared__ float acc_ld[(NPB + 1) * NG];

    const int tid  = threadIdx.x;
    const int base = blockIdx.x * NPB;
    const int nvalid = min(NPB, N - base);

    for (int i = tid; i < TAB; i += 256) {
        const int p = (i >> 3) * ST + (i & 7);
        like_s[p] = tab[i];
        hval_s[p] = tab[TAB + i];
        hidx_s[p] = tab[2 * TAB + i];
    }
    if (tid < nvalid) {
        xs_s[tid] = x[base + tid];
        bs_s[tid] = batch[base + tid];
    }
    __syncthreads();

    const int j0 = bs_s[0];
    const int NJ = bs_s[nvalid - 1] - j0 + 1;

    // zero the used accumulator range
    for (int i = tid; i < NJ * NG; i += 256) acc_ld[i] = 0.f;

    // phase A: coalesced hv/hi writes
    const int s = tid >> 3, g = tid & 7;
    #pragma unroll
    for (int k = 0; k < NPB / 32; ++k) {
        const int i = k * 32 + s;
        if (i >= nvalid) break;
        const int p = xs_s[i] * ST + g;
        out_hv[(size_t)(base + i) * NG + g] = hval_s[p];
        out_hi[(size_t)(base + i) * NG + g] = hidx_s[p];
    }
    __syncthreads();   // acc_ld zeroed by all before phase B atomics

    // phase B: per-thread consecutive chunk, register run-accumulation
    {
        const int i0 = s * KCH;
        float acc = 0.f;
        int jprev = (i0 < nvalid) ? bs_s[i0] : -1;
        #pragma unroll
        for (int t = 0; t < KCH; ++t) {
            const int i = i0 + t;
            if (i >= nvalid) break;
            const int j = bs_s[i];
            if (j != jprev) {
                atomicAdd(&acc_ld[(jprev - j0) * NG + g], acc);
                acc = 0.f; jprev = j;
            }
            acc += like_s[xs_s[i] * ST + g];
        }
        if (jprev >= 0) atomicAdd(&acc_ld[(jprev - j0) * NG + g], acc);
    }
    __syncthreads();

    // phase C: block partial -> global (<=2 contributors per cell chip-wide)
    for (int i = tid; i < NJ * NG; i += 256)
        atomicAdd(&out_like[(size_t)j0 * NG + i], acc_ld[i]);
}

extern "C" void kernel_launch(void* const* d_in, const int* in_sizes, int n_in,
                              void* d_out, int out_size, void* d_ws, size_t ws_size,
                              hipStream_t stream) {
    const float* B     = (const float*)d_in[0];   // (C, M, NG)
    const float* Pi    = (const float*)d_in[1];   // (C, NG)
    const int*   x     = (const int*)d_in[2];     // (N,)
    const int*   batch = (const int*)d_in[3];     // (N,) sorted
    const int N = in_sizes[2];
    const int G = (out_size - 2 * N * NG) / NG;   // out = [G*NG | N*NG | N*NG]

    float* tab = (float*)d_ws;                    // 1536 floats

    float* out_like = (float*)d_out;
    float* out_hv   = out_like + (size_t)G * NG;
    float* out_hi   = out_hv + (size_t)N * NG;

    const int nzb = 8;                            // out_like zeroing blocks

    cgmm_prep<<<nzb + 1, 512, 0, stream>>>(B, Pi, tab, out_like, G, nzb);
    cgmm_nodes<<<(N + NPB - 1) / NPB, 256, 0, stream>>>(x, batch, tab, out_like,
                                                        out_hv, out_hi, N);
}